// Round 5
// baseline (2036.607 us; speedup 1.0000x reference)
//
#include <hip/hip_runtime.h>
#include <math.h>

#define NPTS 2048
#define NB 8
#define R 4        // rows per thread
#define NW 16      // waves per block = column chunks
#define CCH 128    // columns per chunk (NPTS / NW)
#define TILE 8
#define SKIP_MARGIN 44.0f

// ---------------------------------------------------------------------------
// init: packed point records (x,y,z, 0.5*|p|^2), norms |p|, zero potentials,
// zero output. ws is re-poisoned before every timed call.
// ---------------------------------------------------------------------------
__global__ __launch_bounds__(256) void emd_init(const float* __restrict__ x,
                                                const float* __restrict__ y,
                                                float4* __restrict__ x4,
                                                float4* __restrict__ y4,
                                                float* __restrict__ xn,
                                                float* __restrict__ yn,
                                                float* __restrict__ pot0,
                                                float* __restrict__ out) {
  int t = blockIdx.x * blockDim.x + threadIdx.x;  // 0..65535
  if (t < NB * NPTS) {
    float a0 = x[3 * t], a1 = x[3 * t + 1], a2 = x[3 * t + 2];
    float ra = a0 * a0 + a1 * a1 + a2 * a2;
    x4[t] = make_float4(a0, a1, a2, 0.5f * ra);
    xn[t] = sqrtf(ra);
    float b0 = y[3 * t], b1 = y[3 * t + 1], b2 = y[3 * t + 2];
    float rb = b0 * b0 + b1 * b1 + b2 * b2;
    y4[t] = make_float4(b0, b1, b2, 0.5f * rb);
    yn[t] = sqrtf(rb);
  }
  pot0[t] = 0.0f;  // grid exactly covers 4*NB*NPTS
  if (t == 0) out[0] = 0.0f;
}

// ---------------------------------------------------------------------------
// One Sinkhorn softmin sweep over all 4 matrices (geometry as R4 kernel):
// 256 blocks x 1024 threads; block=(mat,b,256-row group); 16 waves = 16
// column chunks of 128; R=4 rows/thread. NEW: per-8-col-tile upper bound
// ub = max(w) + c*max|y| * |x_row| (Cauchy-Schwarz); tiles provably below
// the row's running max - 44 (in log2 units) are skipped wave-uniformly
// (< 2^-33 relative error). Row max seeded with the true diagonal term
// s_{i,i} so skipping is active from the first tile.
// ---------------------------------------------------------------------------
template <bool FINAL>
__global__ __launch_bounds__(1024) void emd_sweep(const float4* __restrict__ x4,
                                                  const float4* __restrict__ y4,
                                                  const float* __restrict__ xn,
                                                  const float* __restrict__ yn,
                                                  const float* __restrict__ pot_in,
                                                  float* __restrict__ pot_out,
                                                  float* __restrict__ out,
                                                  float c,            // log2e/eps
                                                  float neg_eps_ln2,  // -eps*ln2
                                                  float eps_logM) {   // eps*log(2048)
  __shared__ union {
    struct {
      float4 colpack[NPTS];        // 32 KB  (y0,y1,y2, (h_j-0.5|y|^2)*c)
      float tws[256];              // 1 KB   per-tile max of w (scaled)
      float tcn[256];              // 1 KB   per-tile c*max|y_j|
    } mn;
    struct {
      float m[NW][256];            // merge phase (colpack dead)
      float l[NW][256];
    } mg;
  } sh;

  int blk = blockIdx.x;            // 0..255
  int mat = blk >> 6;
  int b = (blk >> 3) & 7;
  int rg = blk & 7;                // 256-row group
  int tid = threadIdx.x;
  int lane = tid & 63;
  int w = tid >> 6;                // 0..15 = column chunk

  const float4* rowp = (mat == 1 || mat == 3) ? y4 : x4;
  const float4* colp = (mat == 0 || mat == 3) ? y4 : x4;
  const float* rown = (mat == 1 || mat == 3) ? yn : xn;
  const float* coln = (mat == 0 || mat == 3) ? yn : xn;
  int hidx = (mat < 2) ? (mat ^ 1) : mat;
  const float* h = pot_in + (hidx * NB + b) * NPTS;
  const float4* colb = colp + b * NPTS;
  const float* colnb = coln + b * NPTS;

  // ---- stage columns + per-tile stats (8 staging lanes == one tile) ----
  {
    float4 q = colb[tid];
    float wa = (h[tid] - q.w) * c;
    sh.mn.colpack[tid] = make_float4(q.x, q.y, q.z, wa);
    float na = colnb[tid];
    float4 q2 = colb[tid + 1024];
    float wb = (h[tid + 1024] - q2.w) * c;
    sh.mn.colpack[tid + 1024] = make_float4(q2.x, q2.y, q2.z, wb);
    float nb = colnb[tid + 1024];
#pragma unroll
    for (int off = 1; off < 8; off <<= 1) {
      wa = fmaxf(wa, __shfl_xor(wa, off));
      na = fmaxf(na, __shfl_xor(na, off));
      wb = fmaxf(wb, __shfl_xor(wb, off));
      nb = fmaxf(nb, __shfl_xor(nb, off));
    }
    if ((tid & 7) == 0) {
      int t0 = tid >> 3;           // 0..127
      sh.mn.tws[t0] = wa;
      sh.mn.tcn[t0] = na * c;
      sh.mn.tws[128 + t0] = wb;
      sh.mn.tcn[128 + t0] = nb * c;
    }
  }
  __syncthreads();

  int rowbase = rg * 256;
  const float4* rowb = rowp + b * NPTS + rowbase;
  const float* rownb = rown + b * NPTS + rowbase;

  float xs[R][3], xnr[R], m[R], l[R];
#pragma unroll
  for (int r = 0; r < R; ++r) {
    int row = r * 64 + lane;
    float4 p = rowb[row];
    xs[r][0] = p.x * c;
    xs[r][1] = p.y * c;
    xs[r][2] = p.z * c;
    xnr[r] = rownb[row];
    // seed running max with true term s_{i,i} (valid lower bound of row max)
    float4 d = sh.mn.colpack[rowbase + row];
    m[r] = fmaf(xs[r][0], d.x, fmaf(xs[r][1], d.y, fmaf(xs[r][2], d.z, d.w)));
    l[r] = 0.0f;
  }

  int j0 = w * CCH;
  int tb = j0 >> 3;                // first tile of this chunk
  for (int tt = 0; tt < CCH / TILE; ++tt) {
    float tws = sh.mn.tws[tb + tt];
    float tcn = sh.mn.tcn[tb + tt];
    bool sk = true;
#pragma unroll
    for (int r = 0; r < R; ++r)
      sk = sk && (fmaf(tcn, xnr[r], tws) < m[r] - SKIP_MARGIN);
    if (__all(sk)) continue;       // provably negligible for all 256 rows

    int jt = j0 + tt * TILE;
    float4 q[8];
#pragma unroll
    for (int k = 0; k < 8; ++k) q[k] = sh.mn.colpack[jt + k];
#pragma unroll
    for (int r = 0; r < R; ++r) {
      float s[8];
#pragma unroll
      for (int k = 0; k < 8; ++k)
        s[k] = fmaf(xs[r][0], q[k].x,
                    fmaf(xs[r][1], q[k].y, fmaf(xs[r][2], q[k].z, q[k].w)));
      float t0 = fmaxf(s[0], s[1]), t1 = fmaxf(s[2], s[3]);
      float t2 = fmaxf(s[4], s[5]), t3 = fmaxf(s[6], s[7]);
      float mt = fmaxf(fmaxf(t0, t1), fmaxf(t2, t3));
      float mn = fmaxf(m[r], mt);
      float acc0 = 0.0f, acc1 = 0.0f;
#pragma unroll
      for (int k = 0; k < 8; k += 2) {
        acc0 += __builtin_amdgcn_exp2f(s[k] - mn);
        acc1 += __builtin_amdgcn_exp2f(s[k + 1] - mn);
      }
      l[r] = fmaf(l[r], __builtin_amdgcn_exp2f(m[r] - mn), acc0 + acc1);
      m[r] = mn;
    }
  }

  __syncthreads();  // colpack dead; safe to overwrite (union)
#pragma unroll
  for (int r = 0; r < R; ++r) {
    sh.mg.m[w][r * 64 + lane] = m[r];
    sh.mg.l[w][r * 64 + lane] = l[r];
  }
  __syncthreads();

  if (w < 4) {
    int row = w * 64 + lane;  // 0..255
    float M = sh.mg.m[0][row];
#pragma unroll
    for (int q = 1; q < NW; ++q) M = fmaxf(M, sh.mg.m[q][row]);
    float L = 0.0f;
#pragma unroll
    for (int q = 0; q < NW; ++q)
      L += sh.mg.l[q][row] * __builtin_amdgcn_exp2f(sh.mg.m[q][row] - M);
    float pw = rowb[row].w;
    float res = pw + neg_eps_ln2 * (M + log2f(L)) + eps_logM;
    if (FINAL) {
      float sign = (mat < 2) ? 1.0f : -1.0f;
      float val = sign * res * (1.0f / (float)(NB * NPTS));
#pragma unroll
      for (int off = 32; off; off >>= 1) val += __shfl_xor(val, off);
      if (lane == 0) atomicAdd(out, val);
    } else {
      const float* oldp = pot_in + (mat * NB + b) * NPTS + rowbase;
      float* outp = pot_out + (mat * NB + b) * NPTS + rowbase;
      outp[row] = 0.5f * (oldp[row] + res);
    }
  }
}

// ---------------------------------------------------------------------------
extern "C" void kernel_launch(void* const* d_in, const int* in_sizes, int n_in,
                              void* d_out, int out_size, void* d_ws, size_t ws_size,
                              hipStream_t stream) {
  const float* x = (const float*)d_in[0];
  const float* y = (const float*)d_in[1];
  float* out = (float*)d_out;

  char* ws = (char*)d_ws;
  float4* x4 = (float4*)ws;                        // 256 KB
  float4* y4 = (float4*)(ws + 262144);             // 256 KB
  float* xn = (float*)(ws + 524288);               // 64 KB
  float* yn = (float*)(ws + 589824);               // 64 KB
  float* pot = (float*)(ws + 655360);              // 2 * 65536 floats

  emd_init<<<256, 256, 0, stream>>>(x, y, x4, y4, xn, yn, pot, out);

  // eps schedule: s=8.0, *=0.9 while s>0.01; eps = f32(s)^2; append 0.01^2
  float eps_arr[80];
  int ne = 0;
  double s = 8.0;
  while (s > 0.01) {
    float sf = (float)s;
    eps_arr[ne++] = sf * sf;
    s *= 0.9;
  }
  {
    float bf = 0.01f;
    eps_arr[ne++] = bf * bf;
  }

  const double LOG2E = 1.4426950408889634;
  const double LN2 = 0.6931471805599453;
  const double LOG2048 = 7.624618986159398;

  int cur = 0;
  for (int k = 0; k < ne; ++k) {
    float eps = eps_arr[k];
    float c = (float)(LOG2E / (double)eps);
    float nel = (float)(-(double)eps * LN2);
    float elM = (float)((double)eps * LOG2048);
    emd_sweep<false><<<256, 1024, 0, stream>>>(x4, y4, xn, yn,
                                               pot + cur * 65536,
                                               pot + (1 - cur) * 65536, out,
                                               c, nel, elM);
    cur ^= 1;
  }

  {
    float eps = eps_arr[ne - 1];
    float c = (float)(LOG2E / (double)eps);
    float nel = (float)(-(double)eps * LN2);
    float elM = (float)((double)eps * LOG2048);
    emd_sweep<true><<<256, 1024, 0, stream>>>(x4, y4, xn, yn,
                                              pot + cur * 65536,
                                              nullptr, out, c, nel, elM);
  }
}